// Round 8
// baseline (221.869 us; speedup 1.0000x reference)
//
#include <hip/hip_runtime.h>

// KDE entropy loss, MI355X/gfx950 — fp8 fused GEMM, symmetric pairs once,
// wrapped-diagonal mapping. R15: LDS-free, barrier-free. Truth table from
// R7-R14: every shared-LDS+barrier variant lands 67-80us with ~45% dual-idle
// (waves/CU 8->80, 16->67, 32->70; -50% LDS traffic -> no gain; +1 barrier
// -> +7.4us). Fix the structure: normalize writes Xn8 in FRAGMENT-MAJOR
// global layout (the verified R7 chunk layout, stored globally), so every
// MFMA fragment is one coalesced global_load_dwordx4 from L2 (4MB input is
// L2-resident). k-loop has no LDS ops, no barriers, no drains — waves are
// independent pipelines. Wave tile 64x128 (2-way B dup = 528MB L2 traffic
// ~= 14.6us @ 36.9TB/s, co-primary with the 14.8us MFMA floor). 128-thr
// blocks (2 waves), grid 1024 = 4 blocks/CU = 2 waves/SIMD; latency hidden
// by ILP (next col-tile's 8 loads prefetched a full MFMA chain ahead).
// ws: [0,4MiB) XnF fp8 frag-major; [4MiB,+64KiB) density f32; then ticket u32.

#define NROWS 16384
#define KDIM 256            // bytes per fp8 row
#define NTILE 128
#define NT (NROWS / NTILE)  // 128 tile rows
#define NSTRIP 8
#define TOTAL_BLOCKS (NT * NSTRIP)  // 1024 blocks of 128 thr = 4 per CU

// sqrt(5 * log2(e)): folded into both operands -> sim scaled by 5*log2(e),
// so kernel = exp2(sim_scaled) = exp(5*sim).
#define SQRT_KLOG2E 2.68579577857f

typedef int i32x4_t __attribute__((ext_vector_type(4)));
typedef int i32x8_t __attribute__((ext_vector_type(8)));
typedef float f32x2_t __attribute__((ext_vector_type(2)));
typedef float f32x16_t __attribute__((ext_vector_type(16)));

#if __has_builtin(__builtin_amdgcn_exp2f)
#define EXP2(x) __builtin_amdgcn_exp2f(x)
#else
#define EXP2(x) exp2f(x)
#endif

union frag8 { i32x8_t v8; i32x4_t v4[2]; };

// Fragment-major layout (== R7's verified LDS chunk layout, global):
// row r, byte kbyte (= kb*64 + h*32 + hh*16 + b, b<16):
//   addr = (r>>5)*8192 + (kb*2+hh)*1024 + h*512 + (r&31)*16 + b
// MFMA operand read (32-row group rg, K-chunk kb, half pp) is then the
// contiguous 1KB at rg*8192 + (kb*2+pp)*1024 + lane*16.

// One wave per row: sqrt(5log2e)/max(||x||,eps), fp8 e4m3 out, scattered
// into fragment-major order; zero density+ticket.
__global__ __launch_bounds__(256)
void kde_normalize(const float* __restrict__ X, unsigned char* __restrict__ XnF,
                   float* __restrict__ density, unsigned int* __restrict__ ticket) {
  const int wave = threadIdx.x >> 6;
  const int lane = threadIdx.x & 63;
  const int row = blockIdx.x * 4 + wave;
  const float4 v = ((const float4*)(X + (size_t)row * KDIM))[lane];
  float ss = v.x * v.x + v.y * v.y + v.z * v.z + v.w * v.w;
  ss += __shfl_xor(ss, 1);
  ss += __shfl_xor(ss, 2);
  ss += __shfl_xor(ss, 4);
  ss += __shfl_xor(ss, 8);
  ss += __shfl_xor(ss, 16);
  ss += __shfl_xor(ss, 32);
  const float scale = SQRT_KLOG2E / fmaxf(sqrtf(ss), 1e-12f);
  int p = 0;
  p = __builtin_amdgcn_cvt_pk_fp8_f32(v.x * scale, v.y * scale, p, false);
  p = __builtin_amdgcn_cvt_pk_fp8_f32(v.z * scale, v.w * scale, p, true);
  // lane holds kbytes [lane*4, +4): piece = lane>>2, chunk = (piece>>2)*2
  // + (piece&1), h = (piece>>1)&1, within-piece = (lane&3)*4.
  const int piece = lane >> 2;
  const size_t addr = (size_t)(row >> 5) * 8192 +
                      (((piece >> 2) * 2 + (piece & 1)) * 1024) +
                      (((piece >> 1) & 1) * 512) + ((row & 31) * 16) +
                      ((lane & 3) * 4);
  *(unsigned int*)(XnF + addr) = (unsigned int)p;
  if (threadIdx.x < 4) density[blockIdx.x * 4 + threadIdx.x] = 0.0f;
  if (blockIdx.x == 0 && threadIdx.x == 0) *ticket = 0u;
}

// Block (bi, s): row tile bi; J = (bi+t) mod 128 for t in [s*8, s*8+8)
// (+ t=64 for s==0, bi<64 — dispatched first so 9-iter blocks start
// earliest). Each unordered tile pair once. 2 waves: wave rg owns rows
// [bi*128 + rg*64, +64) x all 128 J-cols. Per J-iter: 4 col-tile steps of
// 32 cols; per step: prefetch next ct's 8 B-frag loads (ping-pong bA/bB,
// static names), 8 MFMA 32x32x64 fp8 (scale=1 -> exact e4m3; acc born via
// C=0 on kb0), 32 exp2 + packed rowsum adds + 1 half-wave colsum atomic.
// A (64 rows x K256) lives in 64 VGPRs, loaded once, coalesced.
__global__ __launch_bounds__(128, 2)
void kde_gemm(const unsigned char* __restrict__ Xn8, float* __restrict__ density,
              unsigned int* __restrict__ ticket, float* __restrict__ out) {
  __shared__ float red[2];
  __shared__ unsigned int tick_s;

  const int tid = threadIdx.x;
  const int wave = tid >> 6;   // rg 0..1 (64-row half)
  const int lane = tid & 63;
  const int m32 = lane & 31;
  const int h = lane >> 5;
  const int bi = blockIdx.x;
  const int s = blockIdx.y;
  const int t0 = s * 8;
  const int nt = (s == 0 && bi < NT / 2) ? 9 : 8;
  const char* Xb = (const char*)Xn8;
  const int lofs = lane * 16;

  // A fragments: rows bi*128 + wave*64 + rt*32 -> 32-row groups
  // (bi*4 + wave*2 + rt). 16 coalesced dwordx4 loads, 64 VGPR, once.
  frag8 areg[2][4];  // [rt][kb]
#pragma unroll
  for (int rt = 0; rt < 2; rt++)
#pragma unroll
    for (int kb = 0; kb < 4; kb++)
#pragma unroll
      for (int pp = 0; pp < 2; pp++)
        areg[rt][kb].v4[pp] = *(const i32x4_t*)(
            Xb + (size_t)(bi * 4 + wave * 2 + rt) * 8192 +
            (kb * 2 + pp) * 1024 + lofs);

  f32x2_t rs2[2][8];  // rowsums per row-tile, packed pairs
#pragma unroll
  for (int rt = 0; rt < 2; rt++)
#pragma unroll
    for (int r = 0; r < 8; r++) rs2[rt][r] = (f32x2_t)0.0f;

  frag8 bA[4], bB[4];  // ping-pong B fragment buffers (32 VGPR each)

#define LOADB(BUF, J, CT)                                                   \
  {                                                                         \
    const char* pb_ = Xb + (size_t)((J) * 4 + (CT)) * 8192 + lofs;          \
    _Pragma("unroll")                                                       \
    for (int kb = 0; kb < 4; kb++) {                                        \
      BUF[kb].v4[0] = *(const i32x4_t*)(pb_ + (kb * 2) * 1024);             \
      BUF[kb].v4[1] = *(const i32x4_t*)(pb_ + (kb * 2 + 1) * 1024);         \
    }                                                                       \
  }

  // Epilogue for one 32x32 acc: e = exp2(sim_scaled) = exp(5*sim).
  // C/D layout: col = m32, row-in-32 = (r&3) + 8*(r>>2) + 4*h.
#define EPIRT(ACCV, RT)                                                     \
  {                                                                         \
    _Pragma("unroll")                                                       \
    for (int r2 = 0; r2 < 8; r2++) {                                        \
      f32x2_t e;                                                            \
      e.x = EXP2(ACCV[2 * r2]);                                             \
      e.y = EXP2(ACCV[2 * r2 + 1]);                                         \
      rs2[RT][r2] += e; /* v_pk_add_f32 */                                  \
      cacc += e;                                                            \
    }                                                                       \
  }

  // One col-tile step: prefetch next buffer, 8 MFMA, epilogue, colsum.
#define CTSTEP(BUFC, BUFN, CT, PRE, JNEXT, CTN)                             \
  {                                                                         \
    if (PRE) LOADB(BUFN, JNEXT, CTN);                                       \
    f32x16_t a0 = __builtin_amdgcn_mfma_scale_f32_32x32x64_f8f6f4(          \
        areg[0][0].v8, BUFC[0].v8, (f32x16_t)0.0f, 0, 0, 0, 127, 0, 127);   \
    f32x16_t a1 = __builtin_amdgcn_mfma_scale_f32_32x32x64_f8f6f4(          \
        areg[1][0].v8, BUFC[0].v8, (f32x16_t)0.0f, 0, 0, 0, 127, 0, 127);   \
    _Pragma("unroll")                                                       \
    for (int kb = 1; kb < 4; kb++) {                                        \
      a0 = __builtin_amdgcn_mfma_scale_f32_32x32x64_f8f6f4(                 \
          areg[0][kb].v8, BUFC[kb].v8, a0, 0, 0, 0, 127, 0, 127);           \
      a1 = __builtin_amdgcn_mfma_scale_f32_32x32x64_f8f6f4(                 \
          areg[1][kb].v8, BUFC[kb].v8, a1, 0, 0, 0, 127, 0, 127);           \
    }                                                                       \
    f32x2_t cacc = (f32x2_t)0.0f;                                           \
    EPIRT(a0, 0)                                                            \
    EPIRT(a1, 1)                                                            \
    if (t != 0) { /* diagonal tile: rowsum only */                          \
      float cs_ = cacc.x + cacc.y;                                          \
      cs_ += __shfl_xor(cs_, 32); /* combine h halves -> 64-row colsum */   \
      if (h == 0) atomicAdd(&density[Jc * NTILE + (CT) * 32 + m32], cs_);   \
    }                                                                       \
  }

  // Prologue: first J's ct0 into bA.
  int Jc = (bi + t0) & (NT - 1);
  LOADB(bA, Jc, 0);

  for (int k = 0; k < nt; ++k) {
    const int t = (k == 8) ? 64 : (t0 + k);
    Jc = (bi + t) & (NT - 1);
    const bool pre = (k + 1 < nt);
    const int tn = (k + 1 == 8) ? 64 : (t0 + k + 1);
    const int Jn = (bi + tn) & (NT - 1);

    // ct parity is globally static: ct0/ct2 always bA, ct1/ct3 always bB
    // (4 cts/iter, next-J ct0 lands back in bA).
    CTSTEP(bA, bB, 0, true, Jc, 1);
    CTSTEP(bB, bA, 1, true, Jc, 2);
    CTSTEP(bA, bB, 2, true, Jc, 3);
    CTSTEP(bB, bA, 3, pre, Jn, 0);
  }
#undef LOADB
#undef EPIRT
#undef CTSTEP

  // Row epilogue: reduce over 32 cols (m32), scatter; 2 lane-adds/instr.
#pragma unroll
  for (int rt = 0; rt < 2; rt++)
#pragma unroll
    for (int r = 0; r < 16; r++) {
      float v = rs2[rt][r >> 1][r & 1];
      v += __shfl_xor(v, 1);
      v += __shfl_xor(v, 2);
      v += __shfl_xor(v, 4);
      v += __shfl_xor(v, 8);
      v += __shfl_xor(v, 16);
      if (m32 == 0) {
        const int row = bi * NTILE + wave * 64 + rt * 32 +
                        (r & 3) + 8 * (r >> 2) + 4 * h;
        atomicAdd(&density[row], v);
      }
    }

  // Ticket: last finished block computes the entropy (saves 2 launches).
  __syncthreads();  // both waves' atomics issued & drained (vmcnt(0))
  if (tid == 0) {
    __threadfence();
    tick_s = atomicAdd(ticket, 1u);
  }
  __syncthreads();
  if (tick_s == TOTAL_BLOCKS - 1) {
    __threadfence();
    float ssum = 0.0f;
    for (int i = tid; i < NROWS; i += 128) {
      const float d = __hip_atomic_load(&density[i], __ATOMIC_RELAXED,
                                        __HIP_MEMORY_SCOPE_AGENT);
      ssum += logf(d + 1e-9f);
    }
    ssum += __shfl_xor(ssum, 1);
    ssum += __shfl_xor(ssum, 2);
    ssum += __shfl_xor(ssum, 4);
    ssum += __shfl_xor(ssum, 8);
    ssum += __shfl_xor(ssum, 16);
    ssum += __shfl_xor(ssum, 32);
    if (lane == 0) red[wave] = ssum;
    __syncthreads();
    if (tid == 0) out[0] = -(red[0] + red[1]) / (float)NROWS;
  }
}

extern "C" void kernel_launch(void* const* d_in, const int* in_sizes, int n_in,
                              void* d_out, int out_size, void* d_ws, size_t ws_size,
                              hipStream_t stream) {
  const float* X = (const float*)d_in[0];
  float* out = (float*)d_out;
  char* ws = (char*)d_ws;
  unsigned char* XnF = (unsigned char*)ws;
  float* density = (float*)(ws + (size_t)NROWS * KDIM);
  unsigned int* ticket = (unsigned int*)(density + NROWS);

  kde_normalize<<<NROWS / 4, 256, 0, stream>>>(X, XnF, density, ticket);
  kde_gemm<<<dim3(NT, NSTRIP), 128, 0, stream>>>(XnF, density, ticket, out);
}